// Round 1
// baseline (303.510 us; speedup 1.0000x reference)
//
#include <hip/hip_runtime.h>
#include <cmath>

#define S_LEN 2048
#define EMB   1024
#define NHEAD 16
#define DHEAD 64
#define NBATCH 2
#define PIT   72   // LDS pitch (ushorts) for 64-wide bf16 rows: 144B, 16B-aligned, 2-way-bank-free

typedef __attribute__((ext_vector_type(8))) short bf16x8;
typedef __attribute__((ext_vector_type(4))) float f32x4;

__device__ __forceinline__ unsigned short f2bf(float f){
    union { float f; unsigned u; } v; v.f = f;
    unsigned r = v.u + 0x7fffu + ((v.u >> 16) & 1u);
    return (unsigned short)(r >> 16);
}

__device__ __forceinline__ float fast_exp2(float x){
#if __has_builtin(__builtin_amdgcn_exp2f)
    return __builtin_amdgcn_exp2f(x);
#else
    return exp2f(x);
#endif
}

__device__ __forceinline__ float fast_rcp(float x){
#if __has_builtin(__builtin_amdgcn_rcpf)
    return __builtin_amdgcn_rcpf(x);
#else
    return 1.0f / x;
#endif
}

// ---------------- prep: Q (prescaled, exp2-domain) and K -> bf16 [N,H,S,D] ----------------
__global__ void prep_qk(const float* __restrict__ q, const float* __restrict__ k,
                        unsigned short* __restrict__ Qb, unsigned short* __restrict__ Kb){
    const float SC = 0.045084220027780106f;   // log2(e)/32 : folds /sqrt(E) and exp->exp2
    int base = ((int)blockIdx.x * 256 + (int)threadIdx.x) * 4;   // flat over [N,S,E]
    int e = base & (EMB - 1);
    int s = (base >> 10) & (S_LEN - 1);
    int n = base >> 21;
    int h = e >> 6, d = e & 63;
    int dst = ((n*NHEAD + h)*S_LEN + s)*DHEAD + d;
    float4 qv = *(const float4*)(q + base);
    float4 kv = *(const float4*)(k + base);
    uint2 qp, kp;
    qp.x = (unsigned)f2bf(qv.x*SC) | ((unsigned)f2bf(qv.y*SC) << 16);
    qp.y = (unsigned)f2bf(qv.z*SC) | ((unsigned)f2bf(qv.w*SC) << 16);
    kp.x = (unsigned)f2bf(kv.x)    | ((unsigned)f2bf(kv.y)    << 16);
    kp.y = (unsigned)f2bf(kv.z)    | ((unsigned)f2bf(kv.w)    << 16);
    *(uint2*)(Qb + dst) = qp;
    *(uint2*)(Kb + dst) = kp;
}

// ---------------- prep: V -> bf16 transposed [N,H,D,S] ----------------
__global__ void prep_v(const float* __restrict__ v, unsigned short* __restrict__ Vt){
    __shared__ unsigned short tile[64*68];
    const int st = blockIdx.x, h = blockIdx.y, n = blockIdx.z;
    const int tid = threadIdx.x;
    const int sbase = st * 64;
#pragma unroll
    for (int i = 0; i < 4; i++){
        int c = tid + i*256;                 // 1024 chunks: 64 rows x 16 float4
        int srow = c >> 4, c4 = (c & 15) * 4;
        float4 x = *(const float4*)(v + (n*S_LEN + sbase + srow)*EMB + h*DHEAD + c4);
        uint2 p;
        p.x = (unsigned)f2bf(x.x) | ((unsigned)f2bf(x.y) << 16);
        p.y = (unsigned)f2bf(x.z) | ((unsigned)f2bf(x.w) << 16);
        *(uint2*)&tile[srow*68 + c4] = p;
    }
    __syncthreads();
#pragma unroll
    for (int i = 0; i < 2; i++){
        int c = tid + i*256;                 // 512 chunks: 64 d-rows x 8 (16B)
        int d = c >> 3, s8 = (c & 7) * 8;
        unsigned u0 = (unsigned)tile[(s8+0)*68 + d] | ((unsigned)tile[(s8+1)*68 + d] << 16);
        unsigned u1 = (unsigned)tile[(s8+2)*68 + d] | ((unsigned)tile[(s8+3)*68 + d] << 16);
        unsigned u2 = (unsigned)tile[(s8+4)*68 + d] | ((unsigned)tile[(s8+5)*68 + d] << 16);
        unsigned u3 = (unsigned)tile[(s8+6)*68 + d] | ((unsigned)tile[(s8+7)*68 + d] << 16);
        uint4 pk; pk.x = u0; pk.y = u1; pk.z = u2; pk.w = u3;
        *(uint4*)(Vt + ((n*NHEAD + h)*DHEAD + d)*S_LEN + sbase + s8) = pk;
    }
}

// ---------------- prep: mask int32 -> bitmask [N,S,64 words] ----------------
__global__ void prep_mask(const int* __restrict__ mask, unsigned* __restrict__ Mb){
    int w = blockIdx.x*256 + threadIdx.x;          // 0..262143
    const int4* src = (const int4*)(mask) + w*8;   // 32 ints per word
    unsigned bits = 0;
#pragma unroll
    for (int j = 0; j < 8; j++){
        int4 m = src[j];
        if (m.x) bits |= 1u << (j*4+0);
        if (m.y) bits |= 1u << (j*4+1);
        if (m.z) bits |= 1u << (j*4+2);
        if (m.w) bits |= 1u << (j*4+3);
    }
    Mb[w] = bits;
}

// ---------------- prep: W -> bf16 ----------------
__global__ void prep_w(const float* __restrict__ W, unsigned short* __restrict__ Wb){
    int base = (blockIdx.x*256 + threadIdx.x) * 4;
    float4 x = *(const float4*)(W + base);
    uint2 p;
    p.x = (unsigned)f2bf(x.x) | ((unsigned)f2bf(x.y) << 16);
    p.y = (unsigned)f2bf(x.z) | ((unsigned)f2bf(x.w) << 16);
    *(uint2*)(Wb + base) = p;
}

// ---------------- flash attention ----------------
// grid (qt=16, h=16, n=2), block 256 (4 waves). Each wave owns 32 q-rows; BK=64.
__global__ __launch_bounds__(256, 2) void flash_attn(
    const unsigned short* __restrict__ Qb, const unsigned short* __restrict__ Kb,
    const unsigned short* __restrict__ Vt, const unsigned* __restrict__ Mb,
    unsigned short* __restrict__ AttO){
    __shared__ unsigned short Kt[64*PIT];
    __shared__ unsigned short Vl[64*PIT];
    __shared__ unsigned short Pt[4][32*PIT];

    const int n = blockIdx.z, h = blockIdx.y, qt = blockIdx.x;
    const int tid = threadIdx.x;
    const int wave = tid >> 6, lane = tid & 63, il = lane & 15, quad = lane >> 4;
    const int qbase = qt*128 + wave*32;

    const unsigned short* Qh = Qb + (n*NHEAD + h)*S_LEN*DHEAD;
    const unsigned short* Kh = Kb + (n*NHEAD + h)*S_LEN*DHEAD;
    const unsigned short* Vh = Vt + (n*NHEAD + h)*DHEAD*S_LEN;
    const unsigned* Mq = Mb + (n*S_LEN + qbase)*64;

    bf16x8 Qf[2][2];
#pragma unroll
    for (int rt = 0; rt < 2; rt++)
#pragma unroll
        for (int ks = 0; ks < 2; ks++)
            Qf[rt][ks] = *(const bf16x8*)(Qh + (qbase + rt*16 + il)*DHEAD + ks*32 + quad*8);

    f32x4 acc[2][4];
    float mI[2][4], lI[2][4];
#pragma unroll
    for (int rt = 0; rt < 2; rt++)
#pragma unroll
        for (int j = 0; j < 4; j++){
            acc[rt][j] = (f32x4){0.f,0.f,0.f,0.f};
            mI[rt][j] = -1e20f; lI[rt][j] = 0.f;
        }

    unsigned short* Pw = Pt[wave];

    for (int kb = 0; kb < S_LEN; kb += 64){
        // stage K [64k x 64d] and V^T [64d x 64k] tiles
#pragma unroll
        for (int i = 0; i < 2; i++){
            int c = tid + i*256;
            int row = c >> 3, c8 = (c & 7)*8;
            *(uint4*)&Kt[row*PIT + c8] = *(const uint4*)(Kh + (kb + row)*DHEAD + c8);
            *(uint4*)&Vl[row*PIT + c8] = *(const uint4*)(Vh + row*S_LEN + kb + c8);
        }
        __syncthreads();

        bf16x8 Kf[4][2];
#pragma unroll
        for (int t = 0; t < 4; t++)
#pragma unroll
            for (int ks = 0; ks < 2; ks++)
                Kf[t][ks] = *(const bf16x8*)(&Kt[(t*16 + il)*PIT + ks*32 + quad*8]);

#pragma unroll
        for (int rt = 0; rt < 2; rt++){
            f32x4 e[4];
#pragma unroll
            for (int t = 0; t < 4; t++){
                f32x4 z = (f32x4){0.f,0.f,0.f,0.f};
                z    = __builtin_amdgcn_mfma_f32_16x16x32_bf16(Qf[rt][0], Kf[t][0], z, 0, 0, 0);
                e[t] = __builtin_amdgcn_mfma_f32_16x16x32_bf16(Qf[rt][1], Kf[t][1], z, 0, 0, 0);
            }
            // mask (bit==0 -> -1e20); e is already exp2-domain scaled
#pragma unroll
            for (int r = 0; r < 4; r++){
                uint2 mw = *(const uint2*)(Mq + (rt*16 + quad*4 + r)*64 + (kb >> 5));
#pragma unroll
                for (int t = 0; t < 4; t++){
                    unsigned wrd = (t < 2) ? mw.x : mw.y;
                    if (!((wrd >> ((t & 1)*16 + il)) & 1u)) e[t][r] = -1e20f;
                }
            }
            // online softmax update (row stats across 16 lanes of the quad)
            float mx[4], al[4], rs[4], p[4][4];
#pragma unroll
            for (int r = 0; r < 4; r++)
                mx[r] = fmaxf(fmaxf(e[0][r], e[1][r]), fmaxf(e[2][r], e[3][r]));
#pragma unroll
            for (int xm = 1; xm <= 8; xm <<= 1)
#pragma unroll
                for (int r = 0; r < 4; r++)
                    mx[r] = fmaxf(mx[r], __shfl_xor(mx[r], xm, 64));
#pragma unroll
            for (int r = 0; r < 4; r++){
                float mn = fmaxf(mI[rt][r], mx[r]);
                al[r] = fast_exp2(mI[rt][r] - mn);
                mI[rt][r] = mn;
            }
#pragma unroll
            for (int t = 0; t < 4; t++)
#pragma unroll
                for (int r = 0; r < 4; r++)
                    p[t][r] = fast_exp2(e[t][r] - mI[rt][r]);
#pragma unroll
            for (int r = 0; r < 4; r++)
                rs[r] = (p[0][r] + p[1][r]) + (p[2][r] + p[3][r]);
#pragma unroll
            for (int xm = 1; xm <= 8; xm <<= 1)
#pragma unroll
                for (int r = 0; r < 4; r++)
                    rs[r] += __shfl_xor(rs[r], xm, 64);
            f32x4 av;
#pragma unroll
            for (int r = 0; r < 4; r++){
                lI[rt][r] = lI[rt][r]*al[r] + rs[r];
                av[r] = al[r];
            }
#pragma unroll
            for (int dt = 0; dt < 4; dt++)
                acc[rt][dt] *= av;
            // P tile (C-layout -> LDS row-major [q][k])
#pragma unroll
            for (int t = 0; t < 4; t++)
#pragma unroll
                for (int r = 0; r < 4; r++)
                    Pw[(rt*16 + quad*4 + r)*PIT + t*16 + il] = f2bf(p[t][r]);
        }
        // PV: O += P.V  (A-frags from Pw, B-frags from V^T tile)
#pragma unroll
        for (int kk = 0; kk < 2; kk++){
            bf16x8 Pa[2];
#pragma unroll
            for (int rt = 0; rt < 2; rt++)
                Pa[rt] = *(const bf16x8*)(&Pw[(rt*16 + il)*PIT + kk*32 + quad*8]);
#pragma unroll
            for (int dt = 0; dt < 4; dt++){
                bf16x8 Vf = *(const bf16x8*)(&Vl[(dt*16 + il)*PIT + kk*32 + quad*8]);
#pragma unroll
                for (int rt = 0; rt < 2; rt++)
                    acc[rt][dt] = __builtin_amdgcn_mfma_f32_16x16x32_bf16(Pa[rt], Vf, acc[rt][dt], 0, 0, 0);
            }
        }
        __syncthreads();
    }
    // epilogue: normalize and store bf16 [N*S, EMB]
#pragma unroll
    for (int rt = 0; rt < 2; rt++)
#pragma unroll
        for (int r = 0; r < 4; r++){
            float inv = fast_rcp(lI[rt][r]);
            int qrow = n*S_LEN + qbase + rt*16 + quad*4 + r;
#pragma unroll
            for (int dt = 0; dt < 4; dt++)
                AttO[qrow*EMB + h*DHEAD + dt*16 + il] = f2bf(acc[rt][dt][r]*inv);
        }
}

// ---------------- output GEMM: out[4096,1024] = A.W^T + b ----------------
__global__ __launch_bounds__(256, 2) void gemm_out(
    const unsigned short* __restrict__ A, const unsigned short* __restrict__ W,
    const float* __restrict__ bias, float* __restrict__ out){
    __shared__ unsigned short At[128*PIT];
    __shared__ unsigned short Wt[128*PIT];
    const int nb = blockIdx.x, mb = blockIdx.y;
    const int tid = threadIdx.x;
    const int wave = tid >> 6, lane = tid & 63, il = lane & 15, quad = lane >> 4;
    const int wm = wave & 1, wn = wave >> 1;
    const int mbase = mb*128, nbase = nb*128;

    f32x4 acc[4][4];
#pragma unroll
    for (int i = 0; i < 4; i++)
#pragma unroll
        for (int j = 0; j < 4; j++) acc[i][j] = (f32x4){0.f,0.f,0.f,0.f};

    for (int kb = 0; kb < EMB; kb += 64){
#pragma unroll
        for (int i = 0; i < 4; i++){
            int c = tid + i*256;
            int row = c >> 3, c8 = (c & 7)*8;
            *(uint4*)&At[row*PIT + c8] = *(const uint4*)(A + (mbase + row)*EMB + kb + c8);
            *(uint4*)&Wt[row*PIT + c8] = *(const uint4*)(W + (nbase + row)*EMB + kb + c8);
        }
        __syncthreads();
#pragma unroll
        for (int ks = 0; ks < 2; ks++){
            bf16x8 Af[4], Wf[4];
#pragma unroll
            for (int mt = 0; mt < 4; mt++)
                Af[mt] = *(const bf16x8*)(&At[(wm*64 + mt*16 + il)*PIT + ks*32 + quad*8]);
#pragma unroll
            for (int nt = 0; nt < 4; nt++)
                Wf[nt] = *(const bf16x8*)(&Wt[(wn*64 + nt*16 + il)*PIT + ks*32 + quad*8]);
#pragma unroll
            for (int mt = 0; mt < 4; mt++)
#pragma unroll
                for (int nt = 0; nt < 4; nt++)
                    acc[mt][nt] = __builtin_amdgcn_mfma_f32_16x16x32_bf16(Af[mt], Wf[nt], acc[mt][nt], 0, 0, 0);
        }
        __syncthreads();
    }
    float bb[4];
#pragma unroll
    for (int nt = 0; nt < 4; nt++) bb[nt] = bias[nbase + wn*64 + nt*16 + il];
#pragma unroll
    for (int mt = 0; mt < 4; mt++)
#pragma unroll
        for (int nt = 0; nt < 4; nt++)
#pragma unroll
            for (int r = 0; r < 4; r++){
                int row = mbase + wm*64 + mt*16 + quad*4 + r;
                int col = nbase + wn*64 + nt*16 + il;
                out[row*EMB + col] = acc[mt][nt][r] + bb[nt];
            }
}

extern "C" void kernel_launch(void* const* d_in, const int* in_sizes, int n_in,
                              void* d_out, int out_size, void* d_ws, size_t ws_size,
                              hipStream_t stream){
    const float* values = (const float*)d_in[0];
    const float* keys   = (const float*)d_in[1];
    const float* query  = (const float*)d_in[2];
    const int*   mask   = (const int*)d_in[3];
    const float* W_fc   = (const float*)d_in[4];
    const float* b_fc   = (const float*)d_in[5];
    float* out = (float*)d_out;

    char* ws = (char*)d_ws;
    unsigned short* Qb  = (unsigned short*)(ws);                    // 8 MB
    unsigned short* Kb  = (unsigned short*)(ws + (8u << 20));       // 8 MB
    unsigned short* Vtb = (unsigned short*)(ws + (16u << 20));      // 8 MB
    unsigned short* Wb  = (unsigned short*)(ws + (24u << 20));      // 2 MB
    unsigned*       Mbp = (unsigned*)      (ws + (26u << 20));      // 1 MB
    unsigned short* AttO= (unsigned short*)(ws + (27u << 20));      // 8 MB (total 35 MB)

    prep_qk  <<<4096, 256, 0, stream>>>(query, keys, Qb, Kb);
    prep_v   <<<dim3(32, 16, 2), 256, 0, stream>>>(values, Vtb);
    prep_mask<<<1024, 256, 0, stream>>>(mask, Mbp);
    prep_w   <<<1024, 256, 0, stream>>>(W_fc, Wb);
    flash_attn<<<dim3(16, 16, 2), 256, 0, stream>>>(Qb, Kb, Vtb, Mbp, AttO);
    gemm_out <<<dim3(8, 32), 256, 0, stream>>>(AttO, Wb, b_fc, out);
}

// Round 2
// 262.423 us; speedup vs baseline: 1.1566x; 1.1566x over previous
//
#include <hip/hip_runtime.h>
#include <cmath>

#define S_LEN 2048
#define EMB   1024
#define NHEAD 16
#define DHEAD 64
#define PIT   72   // LDS pitch (ushorts): 144B, 16B-aligned, worst 2-way bank alias (free per m136)

typedef __attribute__((ext_vector_type(8))) short bf16x8;
typedef __attribute__((ext_vector_type(4))) float f32x4;

__device__ __forceinline__ unsigned short f2bf(float f){
    union { float f; unsigned u; } v; v.f = f;
    unsigned r = v.u + 0x7fffu + ((v.u >> 16) & 1u);
    return (unsigned short)(r >> 16);
}

__device__ __forceinline__ unsigned pk2bf(float a, float b){
#if __has_builtin(__builtin_amdgcn_cvt_pk_bf16_f32)
    typedef __attribute__((ext_vector_type(2))) __bf16 bf2;
    bf2 r = __builtin_amdgcn_cvt_pk_bf16_f32(a, b);
    return *(unsigned*)&r;
#else
    return (unsigned)f2bf(a) | ((unsigned)f2bf(b) << 16);
#endif
}

__device__ __forceinline__ float fast_exp2(float x){
#if __has_builtin(__builtin_amdgcn_exp2f)
    return __builtin_amdgcn_exp2f(x);
#else
    return exp2f(x);
#endif
}

__device__ __forceinline__ float fast_rcp(float x){
#if __has_builtin(__builtin_amdgcn_rcpf)
    return __builtin_amdgcn_rcpf(x);
#else
    return 1.0f / x;
#endif
}

// ---------------- prep: Q (prescaled, exp2-domain) and K -> bf16 [N,H,S,D] ----------------
__global__ void prep_qk(const float* __restrict__ q, const float* __restrict__ k,
                        unsigned short* __restrict__ Qb, unsigned short* __restrict__ Kb){
    const float SC = 0.045084220027780106f;   // log2(e)/32 : folds /sqrt(E) and exp->exp2
    int base = ((int)blockIdx.x * 256 + (int)threadIdx.x) * 4;   // flat over [N,S,E]
    int e = base & (EMB - 1);
    int s = (base >> 10) & (S_LEN - 1);
    int n = base >> 21;
    int h = e >> 6, d = e & 63;
    int dst = ((n*NHEAD + h)*S_LEN + s)*DHEAD + d;
    float4 qv = *(const float4*)(q + base);
    float4 kv = *(const float4*)(k + base);
    uint2 qp, kp;
    qp.x = pk2bf(qv.x*SC, qv.y*SC);
    qp.y = pk2bf(qv.z*SC, qv.w*SC);
    kp.x = pk2bf(kv.x, kv.y);
    kp.y = pk2bf(kv.z, kv.w);
    *(uint2*)(Qb + dst) = qp;
    *(uint2*)(Kb + dst) = kp;
}

// ---------------- prep: V -> bf16 transposed [N,H,D,S] ----------------
__global__ void prep_v(const float* __restrict__ v, unsigned short* __restrict__ Vt){
    __shared__ unsigned short tile[64*68];
    const int st = blockIdx.x, h = blockIdx.y, n = blockIdx.z;
    const int tid = threadIdx.x;
    const int sbase = st * 64;
#pragma unroll
    for (int i = 0; i < 4; i++){
        int c = tid + i*256;                 // 1024 chunks: 64 rows x 16 float4
        int srow = c >> 4, c4 = (c & 15) * 4;
        float4 x = *(const float4*)(v + (n*S_LEN + sbase + srow)*EMB + h*DHEAD + c4);
        uint2 p;
        p.x = pk2bf(x.x, x.y);
        p.y = pk2bf(x.z, x.w);
        *(uint2*)&tile[srow*68 + c4] = p;
    }
    __syncthreads();
#pragma unroll
    for (int i = 0; i < 2; i++){
        int c = tid + i*256;                 // 512 chunks: 64 d-rows x 8 (16B)
        int d = c >> 3, s8 = (c & 7) * 8;
        unsigned u0 = (unsigned)tile[(s8+0)*68 + d] | ((unsigned)tile[(s8+1)*68 + d] << 16);
        unsigned u1 = (unsigned)tile[(s8+2)*68 + d] | ((unsigned)tile[(s8+3)*68 + d] << 16);
        unsigned u2 = (unsigned)tile[(s8+4)*68 + d] | ((unsigned)tile[(s8+5)*68 + d] << 16);
        unsigned u3 = (unsigned)tile[(s8+6)*68 + d] | ((unsigned)tile[(s8+7)*68 + d] << 16);
        uint4 pk; pk.x = u0; pk.y = u1; pk.z = u2; pk.w = u3;
        *(uint4*)(Vt + ((n*NHEAD + h)*DHEAD + d)*S_LEN + sbase + s8) = pk;
    }
}

// ---------------- prep: mask int32 -> bitmask [N,S,64 words] ----------------
__global__ void prep_mask(const int* __restrict__ mask, unsigned* __restrict__ Mb){
    int w = blockIdx.x*256 + threadIdx.x;          // 0..262143
    const int4* src = (const int4*)(mask) + w*8;   // 32 ints per word
    unsigned bits = 0;
#pragma unroll
    for (int j = 0; j < 8; j++){
        int4 m = src[j];
        if (m.x) bits |= 1u << (j*4+0);
        if (m.y) bits |= 1u << (j*4+1);
        if (m.z) bits |= 1u << (j*4+2);
        if (m.w) bits |= 1u << (j*4+3);
    }
    Mb[w] = bits;
}

// ---------------- prep: W -> bf16 ----------------
__global__ void prep_w(const float* __restrict__ W, unsigned short* __restrict__ Wb){
    int base = (blockIdx.x*256 + threadIdx.x) * 4;
    float4 x = *(const float4*)(W + base);
    uint2 p;
    p.x = pk2bf(x.x, x.y);
    p.y = pk2bf(x.z, x.w);
    *(uint2*)(Wb + base) = p;
}

// ---------------- flash attention, E^T layout, fixed-max softmax, split-K ----------------
// grid (qt=16, h + 16*split, n=2), block 256 (4 waves). Wave owns 32 q-rows; K-tile 64.
// E^T = K.Q^T so C-layout gives lane 4 consecutive k per q -> P packs as ds_write_b64,
// no cross-lane softmax in the loop (fixed-max: shift constant cancels in O/l).
__global__ __launch_bounds__(256, 4) void flash_attn(
    const unsigned short* __restrict__ Qb, const unsigned short* __restrict__ Kb,
    const unsigned short* __restrict__ Vt, const unsigned* __restrict__ Mb,
    float* __restrict__ Op, float* __restrict__ Lp, int klen){
    __shared__ unsigned short Kt[64*PIT];
    __shared__ unsigned short Vl[64*PIT];
    __shared__ unsigned short Pt[4][32*PIT];

    const int n = blockIdx.z, h = blockIdx.y & 15, split = blockIdx.y >> 4;
    const int qt = blockIdx.x;
    const int tid = threadIdx.x;
    const int wave = tid >> 6, lane = tid & 63, il = lane & 15, quad = lane >> 4;
    const int sb = quad*4;
    const int qbase = qt*128 + wave*32;
    const int kbase = split*klen;

    const unsigned short* Qh = Qb + (n*NHEAD + h)*S_LEN*DHEAD;
    const unsigned short* Kh = Kb + (n*NHEAD + h)*S_LEN*DHEAD + kbase*DHEAD;
    const unsigned short* Vh = Vt + (n*NHEAD + h)*DHEAD*S_LEN + kbase;
    const unsigned* Mq0 = Mb + (n*S_LEN + qbase + il)*64 + (kbase >> 5);
    const unsigned* Mq1 = Mq0 + 16*64;

    bf16x8 Qf[2][2];   // B-operand frags: n=il -> q row, k = quad*8+j -> d
#pragma unroll
    for (int rt = 0; rt < 2; rt++)
#pragma unroll
        for (int ks = 0; ks < 2; ks++)
            Qf[rt][ks] = *(const bf16x8*)(Qh + (qbase + rt*16 + il)*DHEAD + ks*32 + quad*8);

    f32x4 acc[2][4];
    float lsum[2] = {0.f, 0.f};
#pragma unroll
    for (int rt = 0; rt < 2; rt++)
#pragma unroll
        for (int j = 0; j < 4; j++) acc[rt][j] = (f32x4){0.f,0.f,0.f,0.f};

    unsigned short* Pw = Pt[wave];

    for (int kb = 0; kb < klen; kb += 64){
        // stage K [64k x 64d] and V^T [64d x 64k]
#pragma unroll
        for (int i = 0; i < 2; i++){
            int c = tid + i*256;
            int row = c >> 3, c8 = (c & 7)*8;
            *(uint4*)&Kt[row*PIT + c8] = *(const uint4*)(Kh + (kb + row)*DHEAD + c8);
            *(uint4*)&Vl[row*PIT + c8] = *(const uint4*)(Vh + row*S_LEN + kb + c8);
        }
        __syncthreads();

        // E^T = K.Q^T : A = K rows, B = Q rows. C: col=il -> q, row=quad*4+r -> k
        f32x4 e[2][4];
#pragma unroll
        for (int t = 0; t < 4; t++){
            bf16x8 kf0 = *(const bf16x8*)(&Kt[(t*16 + il)*PIT + quad*8]);
            bf16x8 kf1 = *(const bf16x8*)(&Kt[(t*16 + il)*PIT + 32 + quad*8]);
#pragma unroll
            for (int rt = 0; rt < 2; rt++){
                f32x4 z = (f32x4){0.f,0.f,0.f,0.f};
                z        = __builtin_amdgcn_mfma_f32_16x16x32_bf16(kf0, Qf[rt][0], z, 0, 0, 0);
                e[rt][t] = __builtin_amdgcn_mfma_f32_16x16x32_bf16(kf1, Qf[rt][1], z, 0, 0, 0);
            }
        }
        // softmax numerators: p = exp2(e), masked -> 0. No max, no rescale.
#pragma unroll
        for (int rt = 0; rt < 2; rt++){
            uint2 mw = *(const uint2*)((rt ? Mq1 : Mq0) + (kb >> 5));
#pragma unroll
            for (int t = 0; t < 4; t++){
                unsigned w = (t & 2) ? mw.y : mw.x;
                float p[4];
#pragma unroll
                for (int r = 0; r < 4; r++){
                    p[r] = fast_exp2(e[rt][t][r]);
                    if (!((w >> ((t & 1)*16 + sb + r)) & 1u)) p[r] = 0.f;
                }
                lsum[rt] += (p[0] + p[1]) + (p[2] + p[3]);
                uint2 pk;
                pk.x = pk2bf(p[0], p[1]);
                pk.y = pk2bf(p[2], p[3]);
                *(uint2*)&Pw[(rt*16 + il)*PIT + t*16 + sb] = pk;   // 4 consecutive k
            }
        }
        // PV: O += P.V (A-frags from Pw rows=q, B-frags from V^T tile)
#pragma unroll
        for (int kk = 0; kk < 2; kk++){
            bf16x8 Pa[2];
#pragma unroll
            for (int rt = 0; rt < 2; rt++)
                Pa[rt] = *(const bf16x8*)(&Pw[(rt*16 + il)*PIT + kk*32 + quad*8]);
#pragma unroll
            for (int dt = 0; dt < 4; dt++){
                bf16x8 Vf = *(const bf16x8*)(&Vl[(dt*16 + il)*PIT + kk*32 + quad*8]);
#pragma unroll
                for (int rt = 0; rt < 2; rt++)
                    acc[rt][dt] = __builtin_amdgcn_mfma_f32_16x16x32_bf16(Pa[rt], Vf, acc[rt][dt], 0, 0, 0);
            }
        }
        __syncthreads();
    }

    // epilogue: write unnormalized O partial (fp32) + l partial
    float lred[2];
#pragma unroll
    for (int rt = 0; rt < 2; rt++){
        float l = lsum[rt];
        l += __shfl_xor(l, 16, 64);
        l += __shfl_xor(l, 32, 64);
        lred[rt] = l;
    }
    float* Ob = Op + (size_t)split*4194304 + (size_t)(n*S_LEN)*EMB + h*DHEAD;
#pragma unroll
    for (int rt = 0; rt < 2; rt++)
#pragma unroll
        for (int dt = 0; dt < 4; dt++)
#pragma unroll
            for (int r = 0; r < 4; r++)
                Ob[(size_t)(qbase + rt*16 + quad*4 + r)*EMB + dt*16 + il] = acc[rt][dt][r];
    if (quad == 0){
#pragma unroll
        for (int rt = 0; rt < 2; rt++)
            Lp[split*65536 + (n*NHEAD + h)*S_LEN + qbase + rt*16 + il] = lred[rt];
    }
}

// ---------------- merge splits + normalize -> bf16 AttO [N*S, EMB] ----------------
__global__ void merge_norm(const float* __restrict__ Op, const float* __restrict__ Lp,
                           unsigned short* __restrict__ AttO, int nsplit){
    int idx = blockIdx.x*256 + threadIdx.x;       // 4096 rows x 256 float4-chunks
    int row = idx >> 8, c4 = (idx & 255)*4;
    int n = row >> 11, q = row & (S_LEN-1), h = c4 >> 6;
    float4 o = *(const float4*)(Op + (size_t)row*EMB + c4);
    float l = Lp[(n*NHEAD + h)*S_LEN + q];
    if (nsplit == 2){
        float4 o1 = *(const float4*)(Op + 4194304 + (size_t)row*EMB + c4);
        o.x += o1.x; o.y += o1.y; o.z += o1.z; o.w += o1.w;
        l += Lp[65536 + (n*NHEAD + h)*S_LEN + q];
    }
    float inv = fast_rcp(l);
    uint2 p;
    p.x = pk2bf(o.x*inv, o.y*inv);
    p.y = pk2bf(o.z*inv, o.w*inv);
    *(uint2*)(AttO + (size_t)row*EMB + c4) = p;
}

// ---------------- output GEMM: out[4096,1024] = A.W^T + b, 64x64 tiles ----------------
__global__ __launch_bounds__(256, 4) void gemm_out(
    const unsigned short* __restrict__ A, const unsigned short* __restrict__ W,
    const float* __restrict__ bias, float* __restrict__ out){
    __shared__ unsigned short At[64*PIT];
    __shared__ unsigned short Wt[64*PIT];
    const int nb = blockIdx.x, mb = blockIdx.y;
    const int tid = threadIdx.x;
    const int wave = tid >> 6, lane = tid & 63, il = lane & 15, quad = lane >> 4;
    const int wm = wave & 1, wn = wave >> 1;
    const int mbase = mb*64, nbase = nb*64;

    f32x4 acc[2][2];
#pragma unroll
    for (int i = 0; i < 2; i++)
#pragma unroll
        for (int j = 0; j < 2; j++) acc[i][j] = (f32x4){0.f,0.f,0.f,0.f};

    for (int kb = 0; kb < EMB; kb += 64){
#pragma unroll
        for (int i = 0; i < 2; i++){
            int c = tid + i*256;
            int row = c >> 3, c8 = (c & 7)*8;
            *(uint4*)&At[row*PIT + c8] = *(const uint4*)(A + (size_t)(mbase + row)*EMB + kb + c8);
            *(uint4*)&Wt[row*PIT + c8] = *(const uint4*)(W + (size_t)(nbase + row)*EMB + kb + c8);
        }
        __syncthreads();
#pragma unroll
        for (int ks = 0; ks < 2; ks++){
            bf16x8 Af[2], Wf[2];
#pragma unroll
            for (int mt = 0; mt < 2; mt++)
                Af[mt] = *(const bf16x8*)(&At[(wm*32 + mt*16 + il)*PIT + ks*32 + quad*8]);
#pragma unroll
            for (int nt = 0; nt < 2; nt++)
                Wf[nt] = *(const bf16x8*)(&Wt[(wn*32 + nt*16 + il)*PIT + ks*32 + quad*8]);
#pragma unroll
            for (int mt = 0; mt < 2; mt++)
#pragma unroll
                for (int nt = 0; nt < 2; nt++)
                    acc[mt][nt] = __builtin_amdgcn_mfma_f32_16x16x32_bf16(Af[mt], Wf[nt], acc[mt][nt], 0, 0, 0);
        }
        __syncthreads();
    }
    float bb[2];
#pragma unroll
    for (int nt = 0; nt < 2; nt++) bb[nt] = bias[nbase + wn*32 + nt*16 + il];
#pragma unroll
    for (int mt = 0; mt < 2; mt++)
#pragma unroll
        for (int nt = 0; nt < 2; nt++)
#pragma unroll
            for (int r = 0; r < 4; r++){
                int row = mbase + wm*32 + mt*16 + quad*4 + r;
                int col = nbase + wn*32 + nt*16 + il;
                out[(size_t)row*EMB + col] = acc[mt][nt][r] + bb[nt];
            }
}

extern "C" void kernel_launch(void* const* d_in, const int* in_sizes, int n_in,
                              void* d_out, int out_size, void* d_ws, size_t ws_size,
                              hipStream_t stream){
    const float* values = (const float*)d_in[0];
    const float* keys   = (const float*)d_in[1];
    const float* query  = (const float*)d_in[2];
    const int*   mask   = (const int*)d_in[3];
    const float* W_fc   = (const float*)d_in[4];
    const float* b_fc   = (const float*)d_in[5];
    float* out = (float*)d_out;

    char* ws = (char*)d_ws;
    unsigned short* Qb  = (unsigned short*)(ws);                    // 8 MB
    unsigned short* Kb  = (unsigned short*)(ws + (8u  << 20));      // 8 MB
    unsigned short* Vtb = (unsigned short*)(ws + (16u << 20));      // 8 MB
    unsigned short* Wb  = (unsigned short*)(ws + (24u << 20));      // 2 MB
    unsigned*       Mbp = (unsigned*)      (ws + (26u << 20));      // 1 MB
    unsigned short* AttO= (unsigned short*)(ws + (27u << 20));      // 8 MB
    float*          Lp  = (float*)         (ws + (35u << 20));      // 0.5 MB (2 splits)
    float*          Opb = (float*)         (ws + (36u << 20));      // 16 MB per split

    // split-K only if workspace can hold 2 fp32 O-partials (total 68 MB)
    int nsplit = (ws_size >= (68ull << 20)) ? 2 : 1;
    int klen = S_LEN / nsplit;

    prep_qk  <<<4096, 256, 0, stream>>>(query, keys, Qb, Kb);
    prep_v   <<<dim3(32, 16, 2), 256, 0, stream>>>(values, Vtb);
    prep_mask<<<1024, 256, 0, stream>>>(mask, Mbp);
    prep_w   <<<1024, 256, 0, stream>>>(W_fc, Wb);
    flash_attn<<<dim3(16, 16*nsplit, 2), 256, 0, stream>>>(Qb, Kb, Vtb, Mbp, Opb, Lp, klen);
    merge_norm<<<4096, 256, 0, stream>>>(Opb, Lp, AttO, nsplit);
    gemm_out <<<dim3(16, 64), 256, 0, stream>>>(AttO, Wb, b_fc, out);
}

// Round 3
// 261.943 us; speedup vs baseline: 1.1587x; 1.0018x over previous
//
#include <hip/hip_runtime.h>
#include <cmath>

#define S_LEN 2048
#define EMB   1024
#define NHEAD 16
#define DHEAD 64
#define PIT   72   // LDS pitch (ushorts): 144B = 16B-aligned, worst 2-way bank alias (free per m136)

typedef __attribute__((ext_vector_type(8))) short bf16x8;
typedef __attribute__((ext_vector_type(4))) float f32x4;

__device__ __forceinline__ unsigned short f2bf(float f){
    union { float f; unsigned u; } v; v.f = f;
    unsigned r = v.u + 0x7fffu + ((v.u >> 16) & 1u);
    return (unsigned short)(r >> 16);
}

__device__ __forceinline__ unsigned pk2bf(float a, float b){
#if __has_builtin(__builtin_amdgcn_cvt_pk_bf16_f32)
    typedef __attribute__((ext_vector_type(2))) __bf16 bf2;
    bf2 r = __builtin_amdgcn_cvt_pk_bf16_f32(a, b);
    return *(unsigned*)&r;
#else
    return (unsigned)f2bf(a) | ((unsigned)f2bf(b) << 16);
#endif
}

__device__ __forceinline__ float fast_exp2(float x){
#if __has_builtin(__builtin_amdgcn_exp2f)
    return __builtin_amdgcn_exp2f(x);
#else
    return exp2f(x);
#endif
}

__device__ __forceinline__ float fast_rcp(float x){
#if __has_builtin(__builtin_amdgcn_rcpf)
    return __builtin_amdgcn_rcpf(x);
#else
    return 1.0f / x;
#endif
}

// ---------------- fused prep: range-dispatched over blockIdx.x ----------------
// [0,4096):    Q (prescaled exp2-domain) + K -> bf16 [N,H,S,D]
// [4096,5120): V -> bf16 transposed [N,H,D,S]
// [5120,6144): W -> bf16
// [6144,14336): mask int32 -> pair AND-masks [N,Sq,Sk/2] uint (halves 0xFFFF/0)
__global__ void prep_all(const float* __restrict__ q, const float* __restrict__ k,
                         const float* __restrict__ v, const int* __restrict__ mask,
                         const float* __restrict__ W,
                         unsigned short* __restrict__ Qb, unsigned short* __restrict__ Kb,
                         unsigned short* __restrict__ Vt, unsigned short* __restrict__ Wb,
                         unsigned* __restrict__ Mp){
    __shared__ unsigned short tile[64*68];
    const int b = blockIdx.x, tid = threadIdx.x;
    if (b < 4096){
        const float SC = 0.045084220027780106f;   // log2(e)/32
        int base = (b*256 + tid) * 4;
        int e = base & (EMB - 1);
        int s = (base >> 10) & (S_LEN - 1);
        int n = base >> 21;
        int h = e >> 6, d = e & 63;
        int dst = ((n*NHEAD + h)*S_LEN + s)*DHEAD + d;
        float4 qv = *(const float4*)(q + base);
        float4 kv = *(const float4*)(k + base);
        uint2 qp, kp;
        qp.x = pk2bf(qv.x*SC, qv.y*SC);
        qp.y = pk2bf(qv.z*SC, qv.w*SC);
        kp.x = pk2bf(kv.x, kv.y);
        kp.y = pk2bf(kv.z, kv.w);
        *(uint2*)(Qb + dst) = qp;
        *(uint2*)(Kb + dst) = kp;
    } else if (b < 5120){
        int idx = b - 4096;
        int st = idx & 31, h = (idx >> 5) & 15, n = idx >> 9;
        int sbase = st * 64;
#pragma unroll
        for (int i = 0; i < 4; i++){
            int c = tid + i*256;
            int srow = c >> 4, c4 = (c & 15) * 4;
            float4 x = *(const float4*)(v + (n*S_LEN + sbase + srow)*EMB + h*DHEAD + c4);
            uint2 p;
            p.x = pk2bf(x.x, x.y);
            p.y = pk2bf(x.z, x.w);
            *(uint2*)&tile[srow*68 + c4] = p;
        }
        __syncthreads();
#pragma unroll
        for (int i = 0; i < 2; i++){
            int c = tid + i*256;
            int d = c >> 3, s8 = (c & 7) * 8;
            unsigned u0 = (unsigned)tile[(s8+0)*68 + d] | ((unsigned)tile[(s8+1)*68 + d] << 16);
            unsigned u1 = (unsigned)tile[(s8+2)*68 + d] | ((unsigned)tile[(s8+3)*68 + d] << 16);
            unsigned u2 = (unsigned)tile[(s8+4)*68 + d] | ((unsigned)tile[(s8+5)*68 + d] << 16);
            unsigned u3 = (unsigned)tile[(s8+6)*68 + d] | ((unsigned)tile[(s8+7)*68 + d] << 16);
            uint4 pk; pk.x = u0; pk.y = u1; pk.z = u2; pk.w = u3;
            *(uint4*)(Vt + ((n*NHEAD + h)*DHEAD + d)*S_LEN + sbase + s8) = pk;
        }
    } else if (b < 6144){
        int base = ((b - 5120)*256 + tid) * 4;
        float4 x = *(const float4*)(W + base);
        uint2 p;
        p.x = pk2bf(x.x, x.y);
        p.y = pk2bf(x.z, x.w);
        *(uint2*)(Wb + base) = p;
    } else {
        int u = (b - 6144)*256 + tid;                 // one int4 -> one uint2
        int4 m = ((const int4*)mask)[u];
        uint2 o;
        o.x = (m.x ? 0xFFFFu : 0u) | (m.y ? 0xFFFF0000u : 0u);
        o.y = (m.z ? 0xFFFFu : 0u) | (m.w ? 0xFFFF0000u : 0u);
        *(uint2*)(Mp + u*2) = o;
    }
}

// ---------------- flash attention, E^T layout, fixed-max softmax, split-K=2 ----------------
// grid (h=16, qt+16*split=32, n=2), block 256 (4 waves). Wave owns 32 q-rows; K-tile 64.
// Mask applied as bitwise AND on packed bf16 pairs; l via MFMA with B=ones.
// Partials accumulated into a zeroed Op/Lp with atomicAdd (2 commuting writers: deterministic).
__global__ __launch_bounds__(256, 4) void flash_attn(
    const unsigned short* __restrict__ Qb, const unsigned short* __restrict__ Kb,
    const unsigned short* __restrict__ Vt, const unsigned* __restrict__ Mp,
    float* __restrict__ Op, float* __restrict__ Lp){
    __shared__ unsigned short Kt[64*PIT];
    __shared__ unsigned short Vl[64*PIT];
    __shared__ unsigned short Pt[4][32*PIT];

    const int n = blockIdx.z, h = blockIdx.x;
    const int qt = blockIdx.y & 15, split = blockIdx.y >> 4;
    const int tid = threadIdx.x;
    const int wave = tid >> 6, lane = tid & 63, il = lane & 15, quad = lane >> 4;
    const int qbase = qt*128 + wave*32;
    const int kbase = split*1024;

    const unsigned short* Qh = Qb + (n*NHEAD + h)*S_LEN*DHEAD;
    const unsigned short* Kh = Kb + (n*NHEAD + h)*S_LEN*DHEAD + kbase*DHEAD;
    const unsigned short* Vh = Vt + (n*NHEAD + h)*DHEAD*S_LEN + kbase;
    // pair-mask row pointers (per-lane): row q = qbase + rt*16 + il, col pairs from kbase/2
    const unsigned* mp0 = Mp + (size_t)(n*S_LEN + qbase + il)*(S_LEN/2) + (kbase >> 1) + quad*2;
    const unsigned* mp1 = mp0 + 16*(S_LEN/2);

    bf16x8 Qf[2][2];   // B-operand frags: n=il -> q row, k = quad*8+j -> d
#pragma unroll
    for (int rt = 0; rt < 2; rt++)
#pragma unroll
        for (int ks = 0; ks < 2; ks++)
            Qf[rt][ks] = *(const bf16x8*)(Qh + (qbase + rt*16 + il)*DHEAD + ks*32 + quad*8);

    f32x4 acc[2][4], accL[2];
#pragma unroll
    for (int rt = 0; rt < 2; rt++){
        accL[rt] = (f32x4){0.f,0.f,0.f,0.f};
#pragma unroll
        for (int j = 0; j < 4; j++) acc[rt][j] = (f32x4){0.f,0.f,0.f,0.f};
    }
    const short onev = 0x3F80;   // bf16 1.0
    const bf16x8 onesb = {onev,onev,onev,onev,onev,onev,onev,onev};

    unsigned short* Pw = Pt[wave];

    for (int kb = 0; kb < 1024; kb += 64){
        // stage K [64k x 64d] and V^T [64d x 64k]
#pragma unroll
        for (int i = 0; i < 2; i++){
            int c = tid + i*256;
            int row = c >> 3, c8 = (c & 7)*8;
            *(uint4*)&Kt[row*PIT + c8] = *(const uint4*)(Kh + (kb + row)*DHEAD + c8);
            *(uint4*)&Vl[row*PIT + c8] = *(const uint4*)(Vh + row*S_LEN + kb + c8);
        }
        __syncthreads();

        // E^T = K.Q^T : A = K rows, B = Q rows. C: col=il -> q, row=quad*4+r -> k
        f32x4 e[2][4];
#pragma unroll
        for (int t = 0; t < 4; t++){
            bf16x8 kf0 = *(const bf16x8*)(&Kt[(t*16 + il)*PIT + quad*8]);
            bf16x8 kf1 = *(const bf16x8*)(&Kt[(t*16 + il)*PIT + 32 + quad*8]);
#pragma unroll
            for (int rt = 0; rt < 2; rt++){
                f32x4 z = (f32x4){0.f,0.f,0.f,0.f};
                z        = __builtin_amdgcn_mfma_f32_16x16x32_bf16(kf0, Qf[rt][0], z, 0, 0, 0);
                e[rt][t] = __builtin_amdgcn_mfma_f32_16x16x32_bf16(kf1, Qf[rt][1], z, 0, 0, 0);
            }
        }
        // p = exp2(e); mask applied as AND on packed bf16 pairs (x*{1,0} == x&{0xFFFF,0})
#pragma unroll
        for (int rt = 0; rt < 2; rt++){
            const unsigned* mp = rt ? mp1 : mp0;
#pragma unroll
            for (int t = 0; t < 4; t++){
                uint2 mw = *(const uint2*)(mp + (kb >> 1) + t*8);
                float p0 = fast_exp2(e[rt][t][0]);
                float p1 = fast_exp2(e[rt][t][1]);
                float p2 = fast_exp2(e[rt][t][2]);
                float p3 = fast_exp2(e[rt][t][3]);
                uint2 pk;
                pk.x = pk2bf(p0, p1) & mw.x;
                pk.y = pk2bf(p2, p3) & mw.y;
                *(uint2*)&Pw[(rt*16 + il)*PIT + t*16 + quad*4] = pk;
            }
        }
        // PV: O += P.V ; l += P.1 (MFMA with B=ones)
#pragma unroll
        for (int kk = 0; kk < 2; kk++){
            bf16x8 Pa[2];
#pragma unroll
            for (int rt = 0; rt < 2; rt++){
                Pa[rt] = *(const bf16x8*)(&Pw[(rt*16 + il)*PIT + kk*32 + quad*8]);
                accL[rt] = __builtin_amdgcn_mfma_f32_16x16x32_bf16(Pa[rt], onesb, accL[rt], 0, 0, 0);
            }
#pragma unroll
            for (int dt = 0; dt < 4; dt++){
                bf16x8 Vf = *(const bf16x8*)(&Vl[(dt*16 + il)*PIT + kk*32 + quad*8]);
#pragma unroll
                for (int rt = 0; rt < 2; rt++)
                    acc[rt][dt] = __builtin_amdgcn_mfma_f32_16x16x32_bf16(Pa[rt], Vf, acc[rt][dt], 0, 0, 0);
            }
        }
        __syncthreads();
    }

    // epilogue: accumulate unnormalized O partial + l partial (atomic; 2 splits commute)
#pragma unroll
    for (int rt = 0; rt < 2; rt++){
#pragma unroll
        for (int dt = 0; dt < 4; dt++)
#pragma unroll
            for (int r = 0; r < 4; r++){
                size_t row = (size_t)(n*S_LEN + qbase + rt*16 + quad*4 + r);
                atomicAdd(&Op[row*EMB + h*DHEAD + dt*16 + il], acc[rt][dt][r]);
            }
        if (il == 0){
#pragma unroll
            for (int r = 0; r < 4; r++)
                atomicAdd(&Lp[(n*NHEAD + h)*S_LEN + qbase + rt*16 + quad*4 + r], accL[rt][r]);
        }
    }
}

// ---------------- normalize -> bf16 AttO [N*S, EMB] ----------------
__global__ void merge_norm(const float* __restrict__ Op, const float* __restrict__ Lp,
                           unsigned short* __restrict__ AttO){
    int idx = blockIdx.x*256 + threadIdx.x;       // 4096 rows x 256 float4-chunks
    int row = idx >> 8, c4 = (idx & 255)*4;
    int n = row >> 11, q = row & (S_LEN-1), h = c4 >> 6;
    float4 o = *(const float4*)(Op + (size_t)row*EMB + c4);
    float l = Lp[(n*NHEAD + h)*S_LEN + q];
    float inv = fast_rcp(l);
    uint2 p;
    p.x = pk2bf(o.x*inv, o.y*inv);
    p.y = pk2bf(o.z*inv, o.w*inv);
    *(uint2*)(AttO + (size_t)row*EMB + c4) = p;
}

// ---------------- output GEMM: out[4096,1024] = A.W^T + b, 64x64 tiles ----------------
__global__ __launch_bounds__(256, 6) void gemm_out(
    const unsigned short* __restrict__ A, const unsigned short* __restrict__ W,
    const float* __restrict__ bias, float* __restrict__ out){
    __shared__ unsigned short At[64*PIT];
    __shared__ unsigned short Wt[64*PIT];
    const int nb = blockIdx.x, mb = blockIdx.y;
    const int tid = threadIdx.x;
    const int wave = tid >> 6, lane = tid & 63, il = lane & 15, quad = lane >> 4;
    const int wm = wave & 1, wn = wave >> 1;
    const int mbase = mb*64, nbase = nb*64;

    f32x4 acc[2][2];
#pragma unroll
    for (int i = 0; i < 2; i++)
#pragma unroll
        for (int j = 0; j < 2; j++) acc[i][j] = (f32x4){0.f,0.f,0.f,0.f};

    for (int kb = 0; kb < EMB; kb += 64){
#pragma unroll
        for (int i = 0; i < 2; i++){
            int c = tid + i*256;
            int row = c >> 3, c8 = (c & 7)*8;
            *(uint4*)&At[row*PIT + c8] = *(const uint4*)(A + (size_t)(mbase + row)*EMB + kb + c8);
            *(uint4*)&Wt[row*PIT + c8] = *(const uint4*)(W + (size_t)(nbase + row)*EMB + kb + c8);
        }
        __syncthreads();
#pragma unroll
        for (int ks = 0; ks < 2; ks++){
            bf16x8 Af[2], Wf[2];
#pragma unroll
            for (int mt = 0; mt < 2; mt++)
                Af[mt] = *(const bf16x8*)(&At[(wm*32 + mt*16 + il)*PIT + ks*32 + quad*8]);
#pragma unroll
            for (int nt = 0; nt < 2; nt++)
                Wf[nt] = *(const bf16x8*)(&Wt[(wn*32 + nt*16 + il)*PIT + ks*32 + quad*8]);
#pragma unroll
            for (int mt = 0; mt < 2; mt++)
#pragma unroll
                for (int nt = 0; nt < 2; nt++)
                    acc[mt][nt] = __builtin_amdgcn_mfma_f32_16x16x32_bf16(Af[mt], Wf[nt], acc[mt][nt], 0, 0, 0);
        }
        __syncthreads();
    }
    float bb[2];
#pragma unroll
    for (int nt = 0; nt < 2; nt++) bb[nt] = bias[nbase + wn*32 + nt*16 + il];
#pragma unroll
    for (int mt = 0; mt < 2; mt++)
#pragma unroll
        for (int nt = 0; nt < 2; nt++)
#pragma unroll
            for (int r = 0; r < 4; r++){
                int row = mbase + wm*32 + mt*16 + quad*4 + r;
                int col = nbase + wn*32 + nt*16 + il;
                out[(size_t)row*EMB + col] = acc[mt][nt][r] + bb[nt];
            }
}

extern "C" void kernel_launch(void* const* d_in, const int* in_sizes, int n_in,
                              void* d_out, int out_size, void* d_ws, size_t ws_size,
                              hipStream_t stream){
    const float* values = (const float*)d_in[0];
    const float* keys   = (const float*)d_in[1];
    const float* query  = (const float*)d_in[2];
    const int*   mask   = (const int*)d_in[3];
    const float* W_fc   = (const float*)d_in[4];
    const float* b_fc   = (const float*)d_in[5];
    float* out = (float*)d_out;

    char* ws = (char*)d_ws;
    unsigned short* Qb  = (unsigned short*)(ws);                        // 8 MB
    unsigned short* Kb  = (unsigned short*)(ws + (8ull  << 20));        // 8 MB
    unsigned short* Vtb = (unsigned short*)(ws + (16ull << 20));        // 8 MB
    unsigned short* Wb  = (unsigned short*)(ws + (24ull << 20));        // 2 MB
    unsigned*       Mp  = (unsigned*)      (ws + (26ull << 20));        // 16 MB
    float*          Op  = (float*)         (ws + (42ull << 20));        // 16 MB (fp32 O accum)
    float*          Lp  = (float*)         (ws + (58ull << 20));        // 256 KB (l accum)
    unsigned short* AttO= (unsigned short*)(ws + (58ull << 20) + (512ull << 10)); // 8 MB -> 66.5 MB total

    // zero the atomic accumulators (Op + Lp contiguous: 16 MB + 256 KB)
    hipMemsetAsync(ws + (42ull << 20), 0, (16ull << 20) + (256ull << 10), stream);

    prep_all  <<<14336, 256, 0, stream>>>(query, keys, values, mask, W_fc, Qb, Kb, Vtb, Wb, Mp);
    flash_attn<<<dim3(16, 32, 2), 256, 0, stream>>>(Qb, Kb, Vtb, Mp, Op, Lp);
    merge_norm<<<4096, 256, 0, stream>>>(Op, Lp, AttO);
    gemm_out  <<<dim3(16, 64), 256, 0, stream>>>(AttO, Wb, b_fc, out);
}

// Round 4
// 258.121 us; speedup vs baseline: 1.1758x; 1.0148x over previous
//
#include <hip/hip_runtime.h>
#include <cmath>

#define S_LEN 2048
#define EMB   1024
#define NHEAD 16
#define DHEAD 64
#define PIT   72   // LDS pitch (ushorts): 144B = 16B-aligned, worst 2-way bank alias (free per m136)

typedef __attribute__((ext_vector_type(8))) short bf16x8;
typedef __attribute__((ext_vector_type(4))) float f32x4;

__device__ __forceinline__ unsigned short f2bf(float f){
    union { float f; unsigned u; } v; v.f = f;
    unsigned r = v.u + 0x7fffu + ((v.u >> 16) & 1u);
    return (unsigned short)(r >> 16);
}

__device__ __forceinline__ unsigned pk2bf(float a, float b){
#if __has_builtin(__builtin_amdgcn_cvt_pk_bf16_f32)
    typedef __attribute__((ext_vector_type(2))) __bf16 bf2;
    bf2 r = __builtin_amdgcn_cvt_pk_bf16_f32(a, b);
    return *(unsigned*)&r;
#else
    return (unsigned)f2bf(a) | ((unsigned)f2bf(b) << 16);
#endif
}

__device__ __forceinline__ float fast_exp2(float x){
#if __has_builtin(__builtin_amdgcn_exp2f)
    return __builtin_amdgcn_exp2f(x);
#else
    return exp2f(x);
#endif
}

__device__ __forceinline__ float fast_rcp(float x){
#if __has_builtin(__builtin_amdgcn_rcpf)
    return __builtin_amdgcn_rcpf(x);
#else
    return 1.0f / x;
#endif
}

// ---------------- fused prep: range-dispatched over blockIdx.x ----------------
// [0,4096):       Q (prescaled exp2-domain) + K -> bf16 [N,H,S,D]
// [4096,5120):    V -> bf16 transposed [N,H,D,S]
// [5120,6144):    W -> bf16
// [6144,14336):   mask int32 -> pair AND-masks [N,Sq,Sk/2] uint (halves 0xFFFF/0)
// [14336,15376):  zero the Op+Lp atomic accumulators (16 MB + 256 KB contiguous)
__global__ void prep_all(const float* __restrict__ q, const float* __restrict__ k,
                         const float* __restrict__ v, const int* __restrict__ mask,
                         const float* __restrict__ W,
                         unsigned short* __restrict__ Qb, unsigned short* __restrict__ Kb,
                         unsigned short* __restrict__ Vt, unsigned short* __restrict__ Wb,
                         unsigned* __restrict__ Mp, float4* __restrict__ Zp){
    __shared__ unsigned short tile[64*68];
    const int b = blockIdx.x, tid = threadIdx.x;
    if (b < 4096){
        const float SC = 0.045084220027780106f;   // log2(e)/32
        int base = (b*256 + tid) * 4;
        int e = base & (EMB - 1);
        int s = (base >> 10) & (S_LEN - 1);
        int n = base >> 21;
        int h = e >> 6, d = e & 63;
        int dst = ((n*NHEAD + h)*S_LEN + s)*DHEAD + d;
        float4 qv = *(const float4*)(q + base);
        float4 kv = *(const float4*)(k + base);
        uint2 qp, kp;
        qp.x = pk2bf(qv.x*SC, qv.y*SC);
        qp.y = pk2bf(qv.z*SC, qv.w*SC);
        kp.x = pk2bf(kv.x, kv.y);
        kp.y = pk2bf(kv.z, kv.w);
        *(uint2*)(Qb + dst) = qp;
        *(uint2*)(Kb + dst) = kp;
    } else if (b < 5120){
        int idx = b - 4096;
        int st = idx & 31, h = (idx >> 5) & 15, n = idx >> 9;
        int sbase = st * 64;
#pragma unroll
        for (int i = 0; i < 4; i++){
            int c = tid + i*256;
            int srow = c >> 4, c4 = (c & 15) * 4;
            float4 x = *(const float4*)(v + (n*S_LEN + sbase + srow)*EMB + h*DHEAD + c4);
            uint2 p;
            p.x = pk2bf(x.x, x.y);
            p.y = pk2bf(x.z, x.w);
            *(uint2*)&tile[srow*68 + c4] = p;
        }
        __syncthreads();
#pragma unroll
        for (int i = 0; i < 2; i++){
            int c = tid + i*256;
            int d = c >> 3, s8 = (c & 7) * 8;
            unsigned u0 = (unsigned)tile[(s8+0)*68 + d] | ((unsigned)tile[(s8+1)*68 + d] << 16);
            unsigned u1 = (unsigned)tile[(s8+2)*68 + d] | ((unsigned)tile[(s8+3)*68 + d] << 16);
            unsigned u2 = (unsigned)tile[(s8+4)*68 + d] | ((unsigned)tile[(s8+5)*68 + d] << 16);
            unsigned u3 = (unsigned)tile[(s8+6)*68 + d] | ((unsigned)tile[(s8+7)*68 + d] << 16);
            uint4 pk; pk.x = u0; pk.y = u1; pk.z = u2; pk.w = u3;
            *(uint4*)(Vt + ((n*NHEAD + h)*DHEAD + d)*S_LEN + sbase + s8) = pk;
        }
    } else if (b < 6144){
        int base = ((b - 5120)*256 + tid) * 4;
        float4 x = *(const float4*)(W + base);
        uint2 p;
        p.x = pk2bf(x.x, x.y);
        p.y = pk2bf(x.z, x.w);
        *(uint2*)(Wb + base) = p;
    } else if (b < 14336){
        int u = (b - 6144)*256 + tid;                 // one int4 -> one uint2
        int4 m = ((const int4*)mask)[u];
        uint2 o;
        o.x = (m.x ? 0xFFFFu : 0u) | (m.y ? 0xFFFF0000u : 0u);
        o.y = (m.z ? 0xFFFFu : 0u) | (m.w ? 0xFFFF0000u : 0u);
        *(uint2*)(Mp + u*2) = o;
    } else {
        int base = (b - 14336)*1024 + tid;            // float4 units; 1040*1024 covers 16.25 MB
        float4 z = {0.f, 0.f, 0.f, 0.f};
#pragma unroll
        for (int i = 0; i < 4; i++)
            Zp[base + i*256] = z;
    }
}

// ---------------- flash attention, E^T layout, fixed-max softmax, split-K=2 ----------------
// grid (qt=16, h+16*split=32, n=2), block 256 (4 waves). Wave owns 32 q-rows; K-tile 64.
// Register-prefetch pipelining: tile i+1's global loads issue right after iter i's first
// barrier and land during iter i's ~1000-cycle compute phase (fixes the serial-latency stall
// that left MFMA=14%/VALU=23%/HBM=13% all idle in round 3).
__global__ __launch_bounds__(256, 4) void flash_attn(
    const unsigned short* __restrict__ Qb, const unsigned short* __restrict__ Kb,
    const unsigned short* __restrict__ Vt, const unsigned* __restrict__ Mp,
    float* __restrict__ Op, float* __restrict__ Lp){
    __shared__ unsigned short Kt[64*PIT];
    __shared__ unsigned short Vl[64*PIT];
    __shared__ unsigned short Pt[4][32*PIT];

    const int n = blockIdx.z;
    const int qt = blockIdx.x;
    const int h = blockIdx.y & 15, split = blockIdx.y >> 4;
    const int tid = threadIdx.x;
    const int wave = tid >> 6, lane = tid & 63, il = lane & 15, quad = lane >> 4;
    const int qbase = qt*128 + wave*32;
    const int kbase = split*1024;

    const unsigned short* Qh = Qb + (n*NHEAD + h)*S_LEN*DHEAD;
    const unsigned short* Kh = Kb + (n*NHEAD + h)*S_LEN*DHEAD + kbase*DHEAD;
    const unsigned short* Vh = Vt + (n*NHEAD + h)*DHEAD*S_LEN + kbase;
    const unsigned* mp0 = Mp + (size_t)(n*S_LEN + qbase + il)*(S_LEN/2) + (kbase >> 1) + quad*2;
    const unsigned* mp1 = mp0 + 16*(S_LEN/2);

    // staging chunk owned by this thread (row r and r+32, 8 cols at c8)
    const int srow = tid >> 3, scol = (tid & 7)*8;

    bf16x8 Qf[2][2];   // B-operand frags: n=il -> q row, k = quad*8+j -> d
#pragma unroll
    for (int rt = 0; rt < 2; rt++)
#pragma unroll
        for (int ks = 0; ks < 2; ks++)
            Qf[rt][ks] = *(const bf16x8*)(Qh + (qbase + rt*16 + il)*DHEAD + ks*32 + quad*8);

    f32x4 acc[2][4], accL[2];
#pragma unroll
    for (int rt = 0; rt < 2; rt++){
        accL[rt] = (f32x4){0.f,0.f,0.f,0.f};
#pragma unroll
        for (int j = 0; j < 4; j++) acc[rt][j] = (f32x4){0.f,0.f,0.f,0.f};
    }
    const short onev = 0x3F80;   // bf16 1.0
    const bf16x8 onesb = {onev,onev,onev,onev,onev,onev,onev,onev};

    unsigned short* Pw = Pt[wave];

    // prefetch tile 0 into registers
    uint4 kpre0 = *(const uint4*)(Kh + srow*DHEAD + scol);
    uint4 kpre1 = *(const uint4*)(Kh + (srow + 32)*DHEAD + scol);
    uint4 vpre0 = *(const uint4*)(Vh + srow*S_LEN + scol);
    uint4 vpre1 = *(const uint4*)(Vh + (srow + 32)*S_LEN + scol);

    for (int kb = 0; kb < 1024; kb += 64){
        // drain prefetch regs into LDS
        *(uint4*)&Kt[srow*PIT + scol]        = kpre0;
        *(uint4*)&Kt[(srow + 32)*PIT + scol] = kpre1;
        *(uint4*)&Vl[srow*PIT + scol]        = vpre0;
        *(uint4*)&Vl[(srow + 32)*PIT + scol] = vpre1;
        __syncthreads();
        // issue next tile's loads; they land during this iter's compute
        if (kb + 64 < 1024){
            kpre0 = *(const uint4*)(Kh + (kb + 64 + srow)*DHEAD + scol);
            kpre1 = *(const uint4*)(Kh + (kb + 64 + srow + 32)*DHEAD + scol);
            vpre0 = *(const uint4*)(Vh + srow*S_LEN + kb + 64 + scol);
            vpre1 = *(const uint4*)(Vh + (srow + 32)*S_LEN + kb + 64 + scol);
        }

        // E^T = K.Q^T : A = K rows, B = Q rows. C: col=il -> q, row=quad*4+r -> k
        f32x4 e[2][4];
#pragma unroll
        for (int t = 0; t < 4; t++){
            bf16x8 kf0 = *(const bf16x8*)(&Kt[(t*16 + il)*PIT + quad*8]);
            bf16x8 kf1 = *(const bf16x8*)(&Kt[(t*16 + il)*PIT + 32 + quad*8]);
#pragma unroll
            for (int rt = 0; rt < 2; rt++){
                f32x4 z = (f32x4){0.f,0.f,0.f,0.f};
                z        = __builtin_amdgcn_mfma_f32_16x16x32_bf16(kf0, Qf[rt][0], z, 0, 0, 0);
                e[rt][t] = __builtin_amdgcn_mfma_f32_16x16x32_bf16(kf1, Qf[rt][1], z, 0, 0, 0);
            }
        }
        // p = exp2(e); mask applied as AND on packed bf16 pairs (x*{1,0} == x&{0xFFFF,0})
#pragma unroll
        for (int rt = 0; rt < 2; rt++){
            const unsigned* mp = rt ? mp1 : mp0;
#pragma unroll
            for (int t = 0; t < 4; t++){
                uint2 mw = *(const uint2*)(mp + (kb >> 1) + t*8);
                float p0 = fast_exp2(e[rt][t][0]);
                float p1 = fast_exp2(e[rt][t][1]);
                float p2 = fast_exp2(e[rt][t][2]);
                float p3 = fast_exp2(e[rt][t][3]);
                uint2 pk;
                pk.x = pk2bf(p0, p1) & mw.x;
                pk.y = pk2bf(p2, p3) & mw.y;
                *(uint2*)&Pw[(rt*16 + il)*PIT + t*16 + quad*4] = pk;
            }
        }
        // PV: O += P.V ; l += P.1 (MFMA with B=ones)
#pragma unroll
        for (int kk = 0; kk < 2; kk++){
            bf16x8 Pa[2];
#pragma unroll
            for (int rt = 0; rt < 2; rt++){
                Pa[rt] = *(const bf16x8*)(&Pw[(rt*16 + il)*PIT + kk*32 + quad*8]);
                accL[rt] = __builtin_amdgcn_mfma_f32_16x16x32_bf16(Pa[rt], onesb, accL[rt], 0, 0, 0);
            }
#pragma unroll
            for (int dt = 0; dt < 4; dt++){
                bf16x8 Vf = *(const bf16x8*)(&Vl[(dt*16 + il)*PIT + kk*32 + quad*8]);
#pragma unroll
                for (int rt = 0; rt < 2; rt++)
                    acc[rt][dt] = __builtin_amdgcn_mfma_f32_16x16x32_bf16(Pa[rt], Vf, acc[rt][dt], 0, 0, 0);
            }
        }
        __syncthreads();
    }

    // epilogue: accumulate unnormalized O partial + l partial (atomic; 2 splits commute)
#pragma unroll
    for (int rt = 0; rt < 2; rt++){
#pragma unroll
        for (int dt = 0; dt < 4; dt++)
#pragma unroll
            for (int r = 0; r < 4; r++){
                size_t row = (size_t)(n*S_LEN + qbase + rt*16 + quad*4 + r);
                atomicAdd(&Op[row*EMB + h*DHEAD + dt*16 + il], acc[rt][dt][r]);
            }
        if (il == 0){
#pragma unroll
            for (int r = 0; r < 4; r++)
                atomicAdd(&Lp[(n*NHEAD + h)*S_LEN + qbase + rt*16 + quad*4 + r], accL[rt][r]);
        }
    }
}

// ---------------- fused normalize + output GEMM: out = (Op/l).W^T + b ----------------
// 128M x 64N tiles, BK=64 (aligned to head dim so h = kb>>6 is iter-constant).
// A-staging reads fp32 Op, multiplies by rcp(l) and packs to bf16 on the fly —
// merge_norm and the AttO buffer are gone. Register-prefetch pipelined like flash.
__global__ __launch_bounds__(256, 2) void gemm_norm(
    const float* __restrict__ Op, const float* __restrict__ Lp,
    const unsigned short* __restrict__ W, const float* __restrict__ bias,
    float* __restrict__ out){
    __shared__ unsigned short At[128*PIT];
    __shared__ unsigned short Wt[64*PIT];
    const int nb = blockIdx.x, mb = blockIdx.y;
    const int tid = threadIdx.x;
    const int wave = tid >> 6, lane = tid & 63, il = lane & 15, quad = lane >> 4;
    const int wm = wave & 1, wn = wave >> 1;
    const int mbase = mb*128, nbase = nb*64;
    const int arow = tid >> 3, acol = (tid & 7)*8;   // A chunks: rows arow+{0,32,64,96}
    const int n_blk = mbase >> 11, qoff = (mbase & (S_LEN-1));
    const float* Lb = Lp + n_blk*NHEAD*S_LEN + qoff;

    f32x4 acc[4][2];
#pragma unroll
    for (int i = 0; i < 4; i++)
#pragma unroll
        for (int j = 0; j < 2; j++) acc[i][j] = (f32x4){0.f,0.f,0.f,0.f};

    float4 apre[4][2]; float lpre[4]; uint4 wpre[2];
    // prefetch kb=0
#pragma unroll
    for (int j = 0; j < 4; j++){
        const float* src = Op + (size_t)(mbase + arow + j*32)*EMB + acol;
        apre[j][0] = *(const float4*)(src);
        apre[j][1] = *(const float4*)(src + 4);
        lpre[j] = Lb[arow + j*32];           // h = 0 at kb = 0
    }
#pragma unroll
    for (int j = 0; j < 2; j++)
        wpre[j] = *(const uint4*)(W + (size_t)(nbase + arow + j*32)*EMB + acol);

    for (int kb = 0; kb < EMB; kb += 64){
        // drain prefetch into LDS (A: normalize + pack to bf16)
#pragma unroll
        for (int j = 0; j < 4; j++){
            float inv = fast_rcp(lpre[j]);
            uint4 pk;
            pk.x = pk2bf(apre[j][0].x*inv, apre[j][0].y*inv);
            pk.y = pk2bf(apre[j][0].z*inv, apre[j][0].w*inv);
            pk.z = pk2bf(apre[j][1].x*inv, apre[j][1].y*inv);
            pk.w = pk2bf(apre[j][1].z*inv, apre[j][1].w*inv);
            *(uint4*)&At[(arow + j*32)*PIT + acol] = pk;
        }
#pragma unroll
        for (int j = 0; j < 2; j++)
            *(uint4*)&Wt[(arow + j*32)*PIT + acol] = wpre[j];
        __syncthreads();
        if (kb + 64 < EMB){
            int h = (kb + 64) >> 6;
#pragma unroll
            for (int j = 0; j < 4; j++){
                const float* src = Op + (size_t)(mbase + arow + j*32)*EMB + kb + 64 + acol;
                apre[j][0] = *(const float4*)(src);
                apre[j][1] = *(const float4*)(src + 4);
                lpre[j] = Lb[h*S_LEN + arow + j*32];
            }
#pragma unroll
            for (int j = 0; j < 2; j++)
                wpre[j] = *(const uint4*)(W + (size_t)(nbase + arow + j*32)*EMB + kb + 64 + acol);
        }
#pragma unroll
        for (int ks = 0; ks < 2; ks++){
            bf16x8 Af[4], Wf[2];
#pragma unroll
            for (int mt = 0; mt < 4; mt++)
                Af[mt] = *(const bf16x8*)(&At[(wm*64 + mt*16 + il)*PIT + ks*32 + quad*8]);
#pragma unroll
            for (int nt = 0; nt < 2; nt++)
                Wf[nt] = *(const bf16x8*)(&Wt[(wn*32 + nt*16 + il)*PIT + ks*32 + quad*8]);
#pragma unroll
            for (int mt = 0; mt < 4; mt++)
#pragma unroll
                for (int nt = 0; nt < 2; nt++)
                    acc[mt][nt] = __builtin_amdgcn_mfma_f32_16x16x32_bf16(Af[mt], Wf[nt], acc[mt][nt], 0, 0, 0);
        }
        __syncthreads();
    }
    float bb[2];
#pragma unroll
    for (int nt = 0; nt < 2; nt++) bb[nt] = bias[nbase + wn*32 + nt*16 + il];
#pragma unroll
    for (int mt = 0; mt < 4; mt++)
#pragma unroll
        for (int nt = 0; nt < 2; nt++)
#pragma unroll
            for (int r = 0; r < 4; r++){
                int row = mbase + wm*64 + mt*16 + quad*4 + r;
                int col = nbase + wn*32 + nt*16 + il;
                out[(size_t)row*EMB + col] = acc[mt][nt][r] + bb[nt];
            }
}

extern "C" void kernel_launch(void* const* d_in, const int* in_sizes, int n_in,
                              void* d_out, int out_size, void* d_ws, size_t ws_size,
                              hipStream_t stream){
    const float* values = (const float*)d_in[0];
    const float* keys   = (const float*)d_in[1];
    const float* query  = (const float*)d_in[2];
    const int*   mask   = (const int*)d_in[3];
    const float* W_fc   = (const float*)d_in[4];
    const float* b_fc   = (const float*)d_in[5];
    float* out = (float*)d_out;

    char* ws = (char*)d_ws;
    unsigned short* Qb  = (unsigned short*)(ws);                        // 8 MB
    unsigned short* Kb  = (unsigned short*)(ws + (8ull  << 20));        // 8 MB
    unsigned short* Vtb = (unsigned short*)(ws + (16ull << 20));        // 8 MB
    unsigned short* Wb  = (unsigned short*)(ws + (24ull << 20));        // 2 MB
    unsigned*       Mp  = (unsigned*)      (ws + (26ull << 20));        // 16 MB
    float*          Opf = (float*)         (ws + (42ull << 20));        // 16 MB (fp32 O accum)
    float*          Lpf = (float*)         (ws + (58ull << 20));        // 256 KB (l accum) -> 58.25 MB

    prep_all <<<15376, 256, 0, stream>>>(query, keys, values, mask, W_fc,
                                         Qb, Kb, Vtb, Wb, Mp, (float4*)Opf);
    flash_attn<<<dim3(16, 32, 2), 256, 0, stream>>>(Qb, Kb, Vtb, Mp, Opf, Lpf);
    gemm_norm<<<dim3(16, 32), 256, 0, stream>>>(Opf, Lpf, Wb, b_fc, out);
}